// Round 2
// baseline (869.573 us; speedup 1.0000x reference)
//
#include <hip/hip_runtime.h>
#include <hip/hip_bf16.h>
#include <stdint.h>

// LinearAttention_9569187136035 — round 2: dtype-adaptive (f32 vs bf16 inputs),
// register-staged bf16 MFMA GEMMs, ws footprint ~50MB, kh/qh parked in d_out.

typedef __bf16 bf16_t;
typedef __bf16 v8bf __attribute__((ext_vector_type(8)));
typedef __bf16 v4bf __attribute__((ext_vector_type(4)));
typedef float  v4f  __attribute__((ext_vector_type(4)));

#define NSPLIT 16

// ---------- dtype detector: flag=1.0 if inputs are f32, 0.0 if bf16 ----------
__global__ __launch_bounds__(256) void detect_kernel(const uint32_t* __restrict__ q,
                                                     float* __restrict__ flag) {
  int t = threadIdx.x;
  float f = __uint_as_float(q[t]);
  // f32 N(0,1) data: finite, 1e-6 < |x| < 100. bf16-pairs as f32: |x| ~ 2^±125 / inf / nan.
  bool sane = (f == f) && fabsf(f) < 100.f && fabsf(f) > 1e-6f;
  unsigned long long m = __ballot(sane);
  __shared__ int cnt[4];
  if ((t & 63) == 0) cnt[t >> 6] = __popcll(m);
  __syncthreads();
  if (t == 0) flag[0] = (cnt[0] + cnt[1] + cnt[2] + cnt[3] >= 128) ? 1.f : 0.f;
}

// rs[o] = -1e9 * sum_e W[o,e] + b[o]; rows 0..1023 = Wq/bq, 1024..2047 = Wk/bk.
__global__ __launch_bounds__(256) void rowsum_kernel(
    const void* __restrict__ Wq, const void* __restrict__ bq,
    const void* __restrict__ Wk, const void* __restrict__ bk,
    const float* __restrict__ flag, float* __restrict__ rs) {
  const bool f32in = flag[0] > 0.5f;
  int w = threadIdx.x >> 6, l = threadIdx.x & 63;
  int row = blockIdx.x * 4 + w;
  int r = (row < 1024) ? row : row - 1024;
  const void* W = (row < 1024) ? Wq : Wk;
  const void* B = (row < 1024) ? bq : bk;
  float s = 0.f;
  if (f32in) {
    const float* p = (const float*)W + (size_t)r * 1024 + l * 16;
#pragma unroll
    for (int i = 0; i < 16; i++) s += p[i];
  } else {
    const bf16_t* p = (const bf16_t*)W + (size_t)r * 1024 + l * 16;
#pragma unroll
    for (int i = 0; i < 16; i++) s += (float)p[i];
  }
#pragma unroll
  for (int sh = 1; sh < 64; sh <<= 1) s += __shfl_xor(s, sh, 64);
  if (l == 0) {
    float b = f32in ? ((const float*)B)[r] : (float)((const bf16_t*)B)[r];
    rs[row] = -1e9f * s + b;
  }
}

// C[m,n] = sum_k A[m,k]*W[n,k] + bias[n]. 128x128 tiles, mfma 16x16x32 bf16,
// register staging (handles f32 or bf16 source per flag).
// EPI 0: plain; masked row -> bias.  EPI 1: per-head softmax; masked row -> softmax(rs).
// EPI 2: masked row -> 0; store dtype per flag (f32 to Cf, else bf16 to Cb).
// AMODE 0: A dtype adaptive; AMODE 1: A is always bf16 (internal buffer).
template <int EPI, int AMODE>
__global__ __launch_bounds__(256) void gemm_nt(
    const void* __restrict__ Ap, const void* __restrict__ Wp_,
    const void* __restrict__ biasp, const int* __restrict__ rowmask,
    const float* __restrict__ rs, const float* __restrict__ flag,
    bf16_t* __restrict__ Cb, float* __restrict__ Cf,
    int M, int N, int K) {
  const bool f32in = flag[0] > 0.5f;
  const bool aF32 = f32in && (AMODE == 0);
  __shared__ __align__(16) bf16_t As[128 * 32];
  __shared__ __align__(16) bf16_t Bs[128 * 32];
  const int t = threadIdx.x;
  const int l = t & 63;
  const int w = t >> 6;
  const int wm = w >> 1, wn = w & 1;
  const int ntiles = N >> 7;
  const int bx = blockIdx.x % ntiles;
  const int by = blockIdx.x / ntiles;
  const int m0 = by << 7, n0 = bx << 7;
  const int c0 = t, c1 = t + 256;   // chunk -> row c>>2, k-off (c&3)*8

  auto ldc = [&](const void* P, bool pf32, int c, int base_row, int kt) -> v8bf {
    int row = base_row + (c >> 2);
    int ko = (c & 3) * 8 + kt;
    if (pf32) {
      const float* p = (const float*)P + (size_t)row * K + ko;
      v4f a = *(const v4f*)p, b = *(const v4f*)(p + 4);
      v8bf o;
#pragma unroll
      for (int j = 0; j < 4; j++) { o[j] = (bf16_t)a[j]; o[4 + j] = (bf16_t)b[j]; }
      return o;
    } else {
      return *(const v8bf*)((const bf16_t*)P + (size_t)row * K + ko);
    }
  };

  const int lr = l & 15;
  const int kq = (l >> 4) * 8;
  const bf16_t* aBase = &As[(wm * 64 + lr) * 32 + kq];
  const bf16_t* bBase = &Bs[(wn * 64 + lr) * 32 + kq];
  v4f acc[4][4] = {};

  for (int kt = 0; kt < K; kt += 32) {
    v8bf a0 = ldc(Ap, aF32, c0, m0, kt);
    v8bf a1 = ldc(Ap, aF32, c1, m0, kt);
    v8bf b0 = ldc(Wp_, f32in, c0, n0, kt);
    v8bf b1 = ldc(Wp_, f32in, c1, n0, kt);
    __syncthreads();
    *(v8bf*)&As[c0 * 8] = a0; *(v8bf*)&As[c1 * 8] = a1;
    *(v8bf*)&Bs[c0 * 8] = b0; *(v8bf*)&Bs[c1 * 8] = b1;
    __syncthreads();
    v8bf af[4], bfr[4];
#pragma unroll
    for (int r = 0; r < 4; r++) af[r] = *(const v8bf*)(aBase + r * 16 * 32);
#pragma unroll
    for (int c = 0; c < 4; c++) bfr[c] = *(const v8bf*)(bBase + c * 16 * 32);
#pragma unroll
    for (int r = 0; r < 4; r++)
#pragma unroll
      for (int c = 0; c < 4; c++)
        acc[r][c] = __builtin_amdgcn_mfma_f32_16x16x32_bf16(af[r], bfr[c], acc[r][c], 0, 0, 0);
  }

  // epilogue: C/D layout col = l&15, row = (l>>4)*4 + i
  const int rq = (l >> 4) * 4;
  float bcol[4], rscol[4]; int colg[4];
#pragma unroll
  for (int c = 0; c < 4; c++) {
    colg[c] = n0 + wn * 64 + c * 16 + lr;
    bcol[c] = f32in ? ((const float*)biasp)[colg[c]] : (float)((const bf16_t*)biasp)[colg[c]];
    rscol[c] = (EPI == 1) ? rs[colg[c]] : 0.f;
  }
#pragma unroll
  for (int r = 0; r < 4; r++) {
    int rowBase = m0 + wm * 64 + r * 16 + rq;
#pragma unroll
    for (int i = 0; i < 4; i++) {
      int row = rowBase + i;
      int msk = rowmask[row];
      float vv[4];
#pragma unroll
      for (int c = 0; c < 4; c++) {
        float x = acc[r][c][i] + bcol[c];
        if (EPI == 0)      x = msk ? x : bcol[c];
        else if (EPI == 1) x = msk ? x : rscol[c];
        else               x = msk ? x : 0.f;
        vv[c] = x;
      }
      if (EPI == 1) {  // per-head softmax: 64 values in this 16-lane group x 4 tiles
        float mx = fmaxf(fmaxf(vv[0], vv[1]), fmaxf(vv[2], vv[3]));
#pragma unroll
        for (int sh = 1; sh < 16; sh <<= 1) mx = fmaxf(mx, __shfl_xor(mx, sh, 64));
        float e0 = __expf(vv[0] - mx), e1 = __expf(vv[1] - mx);
        float e2 = __expf(vv[2] - mx), e3 = __expf(vv[3] - mx);
        float sum = e0 + e1 + e2 + e3;
#pragma unroll
        for (int sh = 1; sh < 16; sh <<= 1) sum += __shfl_xor(sum, sh, 64);
        float rinv = 1.0f / sum;
        vv[0] = e0 * rinv; vv[1] = e1 * rinv; vv[2] = e2 * rinv; vv[3] = e3 * rinv;
      }
#pragma unroll
      for (int c = 0; c < 4; c++) {
        size_t idx = (size_t)row * N + colg[c];
        if (EPI == 2) { if (f32in) Cf[idx] = vv[c]; else Cb[idx] = (bf16_t)vv[c]; }
        else Cb[idx] = (bf16_t)vv[c];
      }
    }
  }
}

// ctx_part[sp][bh][d][e] = sum_{s in chunk} kh[d]*vh[e];  kc_part = sum kh[d]
__global__ __launch_bounds__(256) void ctx_partial(
    const bf16_t* __restrict__ kh, const bf16_t* __restrict__ vh,
    float* __restrict__ ctx_part, float* __restrict__ kc_part) {
  __shared__ __align__(16) float khs[32][64];
  __shared__ __align__(16) float vhs[32][64];
  const int bh = blockIdx.x & 63;
  const int sp = blockIdx.x >> 6;
  const int b = bh >> 4, h = bh & 15;
  const int t = threadIdx.x;
  const int sl = t >> 3, d0 = (t & 7) * 8;
  const int dd = (t & 15) * 4, ee = (t >> 4) * 4;
  float acc[4][4] = {};
  float kcacc = 0.f;
  const size_t base = ((size_t)b * 4096) * 1024 + h * 64;
  const int sBeg = sp * (4096 / NSPLIT), sEnd = sBeg + 4096 / NSPLIT;
  for (int s0 = sBeg; s0 < sEnd; s0 += 32) {
    __syncthreads();
    v8bf kv = *(const v8bf*)(kh + base + (size_t)(s0 + sl) * 1024 + d0);
    v8bf vv = *(const v8bf*)(vh + base + (size_t)(s0 + sl) * 1024 + d0);
#pragma unroll
    for (int j = 0; j < 8; j++) { khs[sl][d0 + j] = (float)kv[j]; vhs[sl][d0 + j] = (float)vv[j]; }
    __syncthreads();
#pragma unroll 4
    for (int s = 0; s < 32; s++) {
      v4f kd = *(const v4f*)&khs[s][dd];
      v4f ve = *(const v4f*)&vhs[s][ee];
#pragma unroll
      for (int x = 0; x < 4; x++)
#pragma unroll
        for (int y = 0; y < 4; y++) acc[x][y] += kd[x] * ve[y];
    }
    if (t < 64) {
#pragma unroll 4
      for (int s = 0; s < 32; s++) kcacc += khs[s][t];
    }
  }
  float* cp = ctx_part + ((size_t)sp * 64 + bh) * 4096;
#pragma unroll
  for (int x = 0; x < 4; x++)
#pragma unroll
    for (int y = 0; y < 4; y++) cp[(dd + x) * 64 + ee + y] = acc[x][y];
  if (t < 64) kc_part[((size_t)sp * 64 + bh) * 64 + t] = kcacc;
}

__global__ __launch_bounds__(256) void reduce_ctx(
    const float* __restrict__ ctx_part, const float* __restrict__ kc_part,
    float* __restrict__ ctx, float* __restrict__ kc) {
  int idx = blockIdx.x * 256 + threadIdx.x;
  if (idx < 64 * 4096) {
    float s = 0.f;
#pragma unroll
    for (int p = 0; p < NSPLIT; p++) s += ctx_part[(size_t)p * 64 * 4096 + idx];
    ctx[idx] = s;
  } else if (idx < 64 * 4096 + 64 * 64) {
    int j = idx - 64 * 4096;
    float s = 0.f;
#pragma unroll
    for (int p = 0; p < NSPLIT; p++) s += kc_part[p * 64 * 64 + j];
    kc[j] = s;
  }
}

// outp = (qh @ ctx) / (qh . kc) + qh   per (b,h), row-wise
__global__ __launch_bounds__(256) void outpre_kernel(
    const bf16_t* __restrict__ qh, const float* __restrict__ ctx,
    const float* __restrict__ kc, bf16_t* __restrict__ outp) {
  __shared__ __align__(16) bf16_t qt[64][256];
  __shared__ __align__(16) float ctxs[64][64];
  __shared__ float kcs[64];
  const int blk = blockIdx.x;
  const int st = blk & 15, h = (blk >> 4) & 15, b = blk >> 8;
  const int bh = b * 16 + h;
  const int t = threadIdx.x;
  const int s0 = st * 256;
  const size_t base = ((size_t)b * 4096 + s0) * 1024 + h * 64;
#pragma unroll
  for (int i = 0; i < 8; i++) {
    int cc = i * 256 + t;
    int row = cc >> 3, dd = (cc & 7) * 8;
    v8bf qv = *(const v8bf*)(qh + base + (size_t)row * 1024 + dd);
#pragma unroll
    for (int j = 0; j < 8; j++) qt[dd + j][row] = qv[j];
  }
  const float* cg = ctx + (size_t)bh * 4096;
#pragma unroll
  for (int i = 0; i < 4; i++) {
    int off = i * 1024 + t * 4;
    *(v4f*)((float*)ctxs + off) = *(const v4f*)(cg + off);
  }
  if (t < 64) kcs[t] = kc[bh * 64 + t];
  __syncthreads();

  const int e0 = (t & 3) * 16;
  const int rg = t >> 2;
  float at[4] = {};
  float acc[4][16] = {};
  for (int d = 0; d < 64; d++) {
    v4bf q4 = *(const v4bf*)&qt[d][rg * 4];
    float kcd = kcs[d];
    float qf[4];
#pragma unroll
    for (int j = 0; j < 4; j++) { qf[j] = (float)q4[j]; at[j] += qf[j] * kcd; }
    const float* cr = &ctxs[d][e0];
    v4f ca = *(const v4f*)cr, cb = *(const v4f*)(cr + 4);
    v4f cc3 = *(const v4f*)(cr + 8), cd = *(const v4f*)(cr + 12);
#pragma unroll
    for (int j = 0; j < 4; j++) {
#pragma unroll
      for (int i = 0; i < 4; i++) {
        acc[j][i]      += qf[j] * ca[i];
        acc[j][4 + i]  += qf[j] * cb[i];
        acc[j][8 + i]  += qf[j] * cc3[i];
        acc[j][12 + i] += qf[j] * cd[i];
      }
    }
  }
#pragma unroll
  for (int j = 0; j < 4; j++) {
    int row = rg * 4 + j;
    float rinv = 1.0f / at[j];
    bf16_t* op = outp + base + (size_t)row * 1024 + e0;
#pragma unroll
    for (int i = 0; i < 16; i++) op[i] = (bf16_t)(acc[j][i] * rinv + (float)qt[e0 + i][row]);
  }
}

extern "C" void kernel_launch(void* const* d_in, const int* in_sizes, int n_in,
                              void* d_out, int out_size, void* d_ws, size_t ws_size,
                              hipStream_t stream) {
  const int* qmask = (const int*)d_in[3];
  const int* kmask = (const int*)d_in[4];
  const int M = 16384, E = 1024;

  char* ws = (char*)d_ws;
  size_t off = 0;
  auto alloc = [&](size_t bytes) {
    void* p = ws + off; off += (bytes + 255) & ~(size_t)255; return p;
  };
  bf16_t* X0   = (bf16_t*)alloc((size_t)M * E * 2);             // 32 MB: vh, then outp
  float* parts = (float*)alloc((size_t)NSPLIT * 64 * 4096 * 4); // 16.8 MB
  float* kcp   = (float*)alloc((size_t)NSPLIT * 64 * 64 * 4);   // 0.26 MB
  float* rs    = (float*)alloc(2048 * 4);
  float* ctx   = (float*)alloc(64 * 4096 * 4);
  float* kc    = (float*)alloc(64 * 64 * 4);
  float* flag  = (float*)alloc(256);
  // kh, then qh live in d_out[0..32MB) (d_out >= 33.5MB in either dtype; final GEMM runs last)
  bf16_t* kh = (bf16_t*)d_out;
  bf16_t* qh = (bf16_t*)d_out;
  bf16_t* vh = X0;
  bf16_t* outp = X0;

  const int gblocks = (M / 128) * (E / 128);
  detect_kernel<<<1, 256, 0, stream>>>((const uint32_t*)d_in[0], flag);
  rowsum_kernel<<<512, 256, 0, stream>>>(d_in[5], d_in[6], d_in[7], d_in[8], flag, rs);
  gemm_nt<1, 0><<<gblocks, 256, 0, stream>>>(d_in[1], d_in[7], d_in[8], kmask, rs + 1024, flag, kh, nullptr, M, E, E);
  gemm_nt<0, 0><<<gblocks, 256, 0, stream>>>(d_in[2], d_in[9], d_in[10], kmask, nullptr, flag, vh, nullptr, M, E, E);
  ctx_partial<<<64 * NSPLIT, 256, 0, stream>>>(kh, vh, parts, kcp);
  reduce_ctx<<<(64 * 4096 + 64 * 64 + 255) / 256, 256, 0, stream>>>(parts, kcp, ctx, kc);
  gemm_nt<1, 0><<<gblocks, 256, 0, stream>>>(d_in[0], d_in[5], d_in[6], qmask, rs, flag, qh, nullptr, M, E, E);
  outpre_kernel<<<1024, 256, 0, stream>>>(qh, ctx, kc, outp);
  gemm_nt<2, 1><<<gblocks, 256, 0, stream>>>(outp, d_in[11], d_in[12], qmask, nullptr, flag, (bf16_t*)d_out, (float*)d_out, M, E, E);
}

// Round 3
// 617.436 us; speedup vs baseline: 1.4084x; 1.4084x over previous
//
#include <hip/hip_runtime.h>
#include <hip/hip_bf16.h>
#include <stdint.h>

// LinearAttention_9569187136035 — round 3: async global_load_lds staging
// (A staged as raw f32, cvt after ds_read; W pre-converted to bf16),
// XCD-aware block swizzle, XOR-granule LDS swizzle, atomic ctx reduction.
// f32 inputs/outputs confirmed in round 2.

typedef __bf16 bf16_t;
typedef __bf16 v8bf __attribute__((ext_vector_type(8)));
typedef __bf16 v4bf __attribute__((ext_vector_type(4)));
typedef float  v4f  __attribute__((ext_vector_type(4)));

#define NSPLIT 8

__device__ __forceinline__ void gl_lds16(const void* g, void* l) {
  __builtin_amdgcn_global_load_lds((const __attribute__((address_space(1))) void*)g,
                                   (__attribute__((address_space(3))) void*)l,
                                   16, 0, 0);
}

// ---- weights f32 -> bf16 (4 matrices of 1M elems into one 8MB ws region) ----
__global__ __launch_bounds__(256) void convert_w(
    const float* __restrict__ W0, const float* __restrict__ W1,
    const float* __restrict__ W2, const float* __restrict__ W3,
    bf16_t* __restrict__ dst)
{
  int g = blockIdx.x * 256 + threadIdx.x;      // 2048 blocks -> g < 524288
  int seg = g >> 17;                            // 131072 v8-chunks per matrix
  int off = (g & 131071) * 8;
  const float* s = (seg == 0 ? W0 : seg == 1 ? W1 : seg == 2 ? W2 : W3) + off;
  v4f a = *(const v4f*)s, b = *(const v4f*)(s + 4);
  v8bf o;
#pragma unroll
  for (int j = 0; j < 4; j++) { o[j] = (bf16_t)a[j]; o[4 + j] = (bf16_t)b[j]; }
  *(v8bf*)(dst + (size_t)seg * 1048576 + off) = o;
}

// rs[o] = -1e9 * sum_e W[o,e] + b[o]; rows 0..1023 = Wq/bq, 1024..2047 = Wk/bk (f32).
__global__ __launch_bounds__(256) void rowsum_kernel(
    const float* __restrict__ Wq, const float* __restrict__ bq,
    const float* __restrict__ Wk, const float* __restrict__ bk,
    float* __restrict__ rs)
{
  int w = threadIdx.x >> 6, l = threadIdx.x & 63;
  int row = blockIdx.x * 4 + w;
  int r = (row < 1024) ? row : row - 1024;
  const float* W = ((row < 1024) ? Wq : Wk) + (size_t)r * 1024 + l * 16;
  float s = 0.f;
#pragma unroll
  for (int i = 0; i < 4; i++) {
    v4f x = *(const v4f*)(W + i * 4);
    s += x[0] + x[1] + x[2] + x[3];
  }
#pragma unroll
  for (int sh = 1; sh < 64; sh <<= 1) s += __shfl_xor(s, sh, 64);
  if (l == 0) {
    float b = (row < 1024) ? bq[r] : bk[r];
    rs[row] = -1e9f * s + b;
  }
}

// C[m,n] = sum_k A[m,k]*W[n,k] + bias[n], M=16384, N=K=1024, 128x128 tiles.
// AF32=1: A is f32 (staged raw into LDS, cvt after ds_read). AF32=0: A bf16.
// EPI 0: plain, masked row -> bias. EPI 1: per-head softmax, masked row -> softmax(rs).
// EPI 2: masked row -> 0, f32 output.
template <int EPI, int AF32>
__global__ __launch_bounds__(256) void gemm_nt(
    const void* __restrict__ Ap, const bf16_t* __restrict__ Wb,
    const float* __restrict__ bias, const int* __restrict__ rowmask,
    const float* __restrict__ rs, void* __restrict__ Cout)
{
  constexpr int K = 1024, N = 1024;
  __shared__ __align__(16) char AsRaw[AF32 ? 16384 : 8192];
  __shared__ __align__(16) bf16_t Bs[128 * 32];

  const int t = threadIdx.x;
  const int l = t & 63;
  const int w = t >> 6;
  const int wm = w >> 1, wn = w & 1;
  // XCD-aware remap: 8 col-tiles of one A row-panel -> consecutive on one XCD
  const int xcd = blockIdx.x & 7;
  const int seq = blockIdx.x >> 3;
  const int by = ((seq >> 3) << 3) + xcd;   // 0..127
  const int bx = seq & 7;                   // 0..7
  const int m0 = by << 7, n0 = bx << 7;

  // --- staging pointers (global granule XOR-swizzled; LDS dest lane-linear) ---
  const bf16_t* bg[2]; bf16_t* bl[2];
#pragma unroll
  for (int i = 0; i < 2; i++) {
    int c = t + 256 * i, row = c >> 2, pg = c & 3;
    int swz = (row & 3) ^ ((row >> 2) & 3);
    bg[i] = Wb + (size_t)(n0 + row) * K + (pg ^ swz) * 8;
    bl[i] = Bs + c * 8;
  }
  const void* ag[4]; void* al[4];
  if (AF32) {
#pragma unroll
    for (int i = 0; i < 4; i++) {
      int c = t + 256 * i, row = c >> 3, pg = c & 7;
      ag[i] = (const float*)Ap + (size_t)(m0 + row) * K + (pg ^ (row & 7)) * 4;
      al[i] = (float*)AsRaw + c * 4;
    }
  } else {
#pragma unroll
    for (int i = 0; i < 2; i++) {
      int c = t + 256 * i, row = c >> 2, pg = c & 3;
      int swz = (row & 3) ^ ((row >> 2) & 3);
      ag[i] = (const bf16_t*)Ap + (size_t)(m0 + row) * K + (pg ^ swz) * 8;
      al[i] = (bf16_t*)AsRaw + c * 8;
    }
  }

  const int lr = l & 15;
  const int g0 = l >> 4;
  const int swzb = (lr & 3) ^ ((lr >> 2) & 3);
  const int bOff = (wn * 64 + lr) * 32 + (g0 ^ swzb) * 8;            // bf16 elems
  const int aOffBf = (wm * 64 + lr) * 32 + (g0 ^ swzb) * 8;          // bf16 elems
  const int aOffF0 = (wm * 64 + lr) * 32 + ((2 * g0) ^ (lr & 7)) * 4;     // f32 elems
  const int aOffF1 = (wm * 64 + lr) * 32 + ((2 * g0 + 1) ^ (lr & 7)) * 4; // f32 elems

  v4f acc[4][4] = {};
  for (int kt = 0; kt < K; kt += 32) {
    __syncthreads();
    if (AF32) {
#pragma unroll
      for (int i = 0; i < 4; i++) gl_lds16((const float*)ag[i] + kt, al[i]);
    } else {
#pragma unroll
      for (int i = 0; i < 2; i++) gl_lds16((const bf16_t*)ag[i] + kt, al[i]);
    }
#pragma unroll
    for (int i = 0; i < 2; i++) gl_lds16(bg[i] + kt, bl[i]);
    __syncthreads();

    v8bf af[4], bf4[4];
    if (AF32) {
      const float* A32 = (const float*)AsRaw;
#pragma unroll
      for (int r = 0; r < 4; r++) {
        v4f x0 = *(const v4f*)(A32 + aOffF0 + r * 512);
        v4f x1 = *(const v4f*)(A32 + aOffF1 + r * 512);
        v8bf o;
#pragma unroll
        for (int j = 0; j < 4; j++) { o[j] = (bf16_t)x0[j]; o[4 + j] = (bf16_t)x1[j]; }
        af[r] = o;
      }
    } else {
      const bf16_t* A16 = (const bf16_t*)AsRaw;
#pragma unroll
      for (int r = 0; r < 4; r++) af[r] = *(const v8bf*)(A16 + aOffBf + r * 512);
    }
#pragma unroll
    for (int c = 0; c < 4; c++) bf4[c] = *(const v8bf*)(Bs + bOff + c * 512);
#pragma unroll
    for (int r = 0; r < 4; r++)
#pragma unroll
      for (int c = 0; c < 4; c++)
        acc[r][c] = __builtin_amdgcn_mfma_f32_16x16x32_bf16(af[r], bf4[c], acc[r][c], 0, 0, 0);
  }

  // epilogue: C/D layout col = l&15, row = (l>>4)*4 + i
  const int rq = (l >> 4) * 4;
  float bcol[4], rscol[4]; int colg[4];
#pragma unroll
  for (int c = 0; c < 4; c++) {
    colg[c] = n0 + wn * 64 + c * 16 + lr;
    bcol[c] = bias[colg[c]];
    rscol[c] = (EPI == 1) ? rs[colg[c]] : 0.f;
  }
#pragma unroll
  for (int r = 0; r < 4; r++) {
    int rowBase = m0 + wm * 64 + r * 16 + rq;
#pragma unroll
    for (int i = 0; i < 4; i++) {
      int row = rowBase + i;
      int msk = rowmask[row];
      float vv[4];
#pragma unroll
      for (int c = 0; c < 4; c++) {
        float x = acc[r][c][i] + bcol[c];
        if (EPI == 0)      x = msk ? x : bcol[c];
        else if (EPI == 1) x = msk ? x : rscol[c];
        else               x = msk ? x : 0.f;
        vv[c] = x;
      }
      if (EPI == 1) {  // per-head softmax: 64 vals in this 16-lane group x 4 tiles
        float mx = fmaxf(fmaxf(vv[0], vv[1]), fmaxf(vv[2], vv[3]));
#pragma unroll
        for (int sh = 1; sh < 16; sh <<= 1) mx = fmaxf(mx, __shfl_xor(mx, sh, 64));
        float e0 = __expf(vv[0] - mx), e1 = __expf(vv[1] - mx);
        float e2 = __expf(vv[2] - mx), e3 = __expf(vv[3] - mx);
        float sum = e0 + e1 + e2 + e3;
#pragma unroll
        for (int sh = 1; sh < 16; sh <<= 1) sum += __shfl_xor(sum, sh, 64);
        float rinv = 1.0f / sum;
        vv[0] = e0 * rinv; vv[1] = e1 * rinv; vv[2] = e2 * rinv; vv[3] = e3 * rinv;
      }
#pragma unroll
      for (int c = 0; c < 4; c++) {
        size_t idx = (size_t)row * N + colg[c];
        if (EPI == 2) ((float*)Cout)[idx] = vv[c];
        else          ((bf16_t*)Cout)[idx] = (bf16_t)vv[c];
      }
    }
  }
}

// ctx[bh][d][e] += sum_{s chunk} kh[d]*vh[e];  kc[bh][d] += sum kh[d]  (f32 atomics)
__global__ __launch_bounds__(256) void ctx_partial(
    const bf16_t* __restrict__ kh, const bf16_t* __restrict__ vh,
    float* __restrict__ ctx, float* __restrict__ kc)
{
  __shared__ __align__(16) float khs[32][64];
  __shared__ __align__(16) float vhs[32][64];
  const int bh = blockIdx.x & 63;
  const int sp = blockIdx.x >> 6;
  const int b = bh >> 4, h = bh & 15;
  const int t = threadIdx.x;
  const int sl = t >> 3, d0 = (t & 7) * 8;
  const int dd = (t & 15) * 4, ee = (t >> 4) * 4;
  float acc[4][4] = {};
  float kcacc = 0.f;
  const size_t base = ((size_t)b * 4096) * 1024 + h * 64;
  const int sBeg = sp * (4096 / NSPLIT), sEnd = sBeg + 4096 / NSPLIT;
  for (int s0 = sBeg; s0 < sEnd; s0 += 32) {
    __syncthreads();
    v8bf kv = *(const v8bf*)(kh + base + (size_t)(s0 + sl) * 1024 + d0);
    v8bf vv = *(const v8bf*)(vh + base + (size_t)(s0 + sl) * 1024 + d0);
#pragma unroll
    for (int j = 0; j < 8; j++) { khs[sl][d0 + j] = (float)kv[j]; vhs[sl][d0 + j] = (float)vv[j]; }
    __syncthreads();
#pragma unroll 4
    for (int s = 0; s < 32; s++) {
      v4f kd = *(const v4f*)&khs[s][dd];
      v4f ve = *(const v4f*)&vhs[s][ee];
#pragma unroll
      for (int x = 0; x < 4; x++)
#pragma unroll
        for (int y = 0; y < 4; y++) acc[x][y] += kd[x] * ve[y];
    }
    if (t < 64) {
#pragma unroll 4
      for (int s = 0; s < 32; s++) kcacc += khs[s][t];
    }
  }
  float* cp = ctx + (size_t)bh * 4096;
#pragma unroll
  for (int x = 0; x < 4; x++)
#pragma unroll
    for (int y = 0; y < 4; y++) atomicAdd(&cp[(dd + x) * 64 + ee + y], acc[x][y]);
  if (t < 64) atomicAdd(&kc[bh * 64 + t], kcacc);
}

// outp = (qh @ ctx) / (qh . kc) + qh   per (b,h)
__global__ __launch_bounds__(256) void outpre_kernel(
    const bf16_t* __restrict__ qh, const float* __restrict__ ctx,
    const float* __restrict__ kc, bf16_t* __restrict__ outp)
{
  __shared__ __align__(16) bf16_t qt[64][256];
  __shared__ __align__(16) float ctxs[64][64];
  __shared__ float kcs[64];
  const int blk = blockIdx.x;
  const int st = blk & 15, h = (blk >> 4) & 15, b = blk >> 8;
  const int bh = b * 16 + h;
  const int t = threadIdx.x;
  const int s0 = st * 256;
  const size_t base = ((size_t)b * 4096 + s0) * 1024 + h * 64;
#pragma unroll
  for (int i = 0; i < 8; i++) {
    int cc = i * 256 + t;
    int row = cc >> 3, dd = (cc & 7) * 8;
    v8bf qv = *(const v8bf*)(qh + base + (size_t)row * 1024 + dd);
#pragma unroll
    for (int j = 0; j < 8; j++) qt[dd + j][row] = qv[j];
  }
  const float* cg = ctx + (size_t)bh * 4096;
#pragma unroll
  for (int i = 0; i < 4; i++) {
    int off = i * 1024 + t * 4;
    *(v4f*)((float*)ctxs + off) = *(const v4f*)(cg + off);
  }
  if (t < 64) kcs[t] = kc[bh * 64 + t];
  __syncthreads();

  const int e0 = (t & 3) * 16;
  const int rg = t >> 2;
  float at[4] = {};
  float acc[4][16] = {};
  for (int d = 0; d < 64; d++) {
    v4bf q4 = *(const v4bf*)&qt[d][rg * 4];
    float kcd = kcs[d];
    float qf[4];
#pragma unroll
    for (int j = 0; j < 4; j++) { qf[j] = (float)q4[j]; at[j] += qf[j] * kcd; }
    const float* cr = &ctxs[d][e0];
    v4f ca = *(const v4f*)cr, cb = *(const v4f*)(cr + 4);
    v4f cc3 = *(const v4f*)(cr + 8), cd = *(const v4f*)(cr + 12);
#pragma unroll
    for (int j = 0; j < 4; j++) {
#pragma unroll
      for (int i = 0; i < 4; i++) {
        acc[j][i]      += qf[j] * ca[i];
        acc[j][4 + i]  += qf[j] * cb[i];
        acc[j][8 + i]  += qf[j] * cc3[i];
        acc[j][12 + i] += qf[j] * cd[i];
      }
    }
  }
#pragma unroll
  for (int j = 0; j < 4; j++) {
    int row = rg * 4 + j;
    float rinv = 1.0f / at[j];
    bf16_t* op = outp + base + (size_t)row * 1024 + e0;
#pragma unroll
    for (int i = 0; i < 16; i++) op[i] = (bf16_t)(acc[j][i] * rinv + (float)qt[e0 + i][row]);
  }
}

extern "C" void kernel_launch(void* const* d_in, const int* in_sizes, int n_in,
                              void* d_out, int out_size, void* d_ws, size_t ws_size,
                              hipStream_t stream)
{
  const float* q  = (const float*)d_in[0];
  const float* k  = (const float*)d_in[1];
  const float* v  = (const float*)d_in[2];
  const int* qmask = (const int*)d_in[3];
  const int* kmask = (const int*)d_in[4];
  const float* Wq = (const float*)d_in[5];
  const float* bq = (const float*)d_in[6];
  const float* Wk = (const float*)d_in[7];
  const float* bk = (const float*)d_in[8];
  const float* Wv = (const float*)d_in[9];
  const float* bv = (const float*)d_in[10];
  const float* Wp = (const float*)d_in[11];
  const float* bp = (const float*)d_in[12];

  const int M = 16384;
  char* ws = (char*)d_ws;
  size_t off = 0;
  auto alloc = [&](size_t bytes) {
    void* p = ws + off; off += (bytes + 255) & ~(size_t)255; return p;
  };
  bf16_t* wb   = (bf16_t*)alloc(4 * 1048576 * 2);           // Wq,Wk,Wv,Wp bf16 (8 MB)
  bf16_t* outp = (bf16_t*)alloc((size_t)M * 1024 * 2);      // 33.5 MB
  float* ctx   = (float*)alloc((64 * 4096 + 64 * 64) * 4);  // ctx + kc contiguous (1.06 MB)
  float* kc    = ctx + 64 * 4096;
  float* rs    = (float*)alloc(2048 * 4);
  // total ws ~= 43 MB (round 2 proved >= 49.3 usable)
  bf16_t* Wqb = wb, *Wkb = wb + 1048576, *Wvb = wb + 2097152, *Wpb = wb + 3145728;
  // kh (then qh) at d_out[0:33.5MB), vh at d_out[33.5:67MB); final f32 C overwrites all
  bf16_t* kh = (bf16_t*)d_out;
  bf16_t* qh = (bf16_t*)d_out;
  bf16_t* vh = (bf16_t*)((char*)d_out + 33554432);

  hipMemsetAsync(ctx, 0, (64 * 4096 + 64 * 64) * 4, stream);
  convert_w<<<2048, 256, 0, stream>>>(Wq, Wk, Wv, Wp, wb);
  rowsum_kernel<<<512, 256, 0, stream>>>(Wq, bq, Wk, bk, rs);
  const int gblocks = (M / 128) * (1024 / 128);  // 1024
  gemm_nt<1, 1><<<gblocks, 256, 0, stream>>>(k, Wkb, bk, kmask, rs + 1024, kh);
  gemm_nt<0, 1><<<gblocks, 256, 0, stream>>>(v, Wvb, bv, kmask, nullptr, vh);
  ctx_partial<<<64 * NSPLIT, 256, 0, stream>>>(kh, vh, ctx, kc);
  gemm_nt<1, 1><<<gblocks, 256, 0, stream>>>(q, Wqb, bq, qmask, rs, qh);
  outpre_kernel<<<1024, 256, 0, stream>>>(qh, ctx, kc, outp);
  gemm_nt<2, 0><<<gblocks, 256, 0, stream>>>(outp, Wpb, bp, qmask, nullptr, d_out);
}

// Round 4
// 569.326 us; speedup vs baseline: 1.5274x; 1.0845x over previous
//
#include <hip/hip_runtime.h>
#include <hip/hip_bf16.h>
#include <stdint.h>

// LinearAttention_9569187136035 — round 4: bf16 pre-convert of q/k/v +
// double-buffered async GEMM K-loop (sync -> prefetch -> compute), linear LDS
// layout, XCD-aware swizzle kept. f32 in/out; ws ~43 MB; d_out used as scratch.

typedef __bf16 bf16_t;
typedef __bf16 v8bf __attribute__((ext_vector_type(8)));
typedef __bf16 v4bf __attribute__((ext_vector_type(4)));
typedef float  v4f  __attribute__((ext_vector_type(4)));

#define NSPLIT 16

__device__ __forceinline__ void gl_lds16(const void* g, void* l) {
  __builtin_amdgcn_global_load_lds((const __attribute__((address_space(1))) void*)g,
                                   (__attribute__((address_space(3))) void*)l,
                                   16, 0, 0);
}

// ---- weights f32 -> bf16 (Wq,Wk,Wv,Wp -> 8MB ws region) ----
__global__ __launch_bounds__(256) void convert_w(
    const float* __restrict__ W0, const float* __restrict__ W1,
    const float* __restrict__ W2, const float* __restrict__ W3,
    bf16_t* __restrict__ dst)
{
  int g = blockIdx.x * 256 + threadIdx.x;      // 2048 blocks
  int seg = g >> 17;
  int off = (g & 131071) * 8;
  const float* s = (seg == 0 ? W0 : seg == 1 ? W1 : seg == 2 ? W2 : W3) + off;
  v4f a = *(const v4f*)s, b = *(const v4f*)(s + 4);
  v8bf o;
#pragma unroll
  for (int j = 0; j < 4; j++) { o[j] = (bf16_t)a[j]; o[4 + j] = (bf16_t)b[j]; }
  *(v8bf*)(dst + (size_t)seg * 1048576 + off) = o;
}

// ---- activation f32 -> bf16: two tensors in one launch (8192 blocks each) ----
__global__ __launch_bounds__(256) void convert_kv_kernel(
    const float* __restrict__ k, const float* __restrict__ v,
    bf16_t* __restrict__ kb, bf16_t* __restrict__ vb)
{
  int bid = blockIdx.x;
  const float* s; bf16_t* d;
  if (bid < 8192) { s = k; d = kb; } else { s = v; d = vb; bid -= 8192; }
  size_t i = ((size_t)bid * 256 + threadIdx.x) * 8;
  v4f a = *(const v4f*)(s + i), b = *(const v4f*)(s + i + 4);
  v8bf o;
#pragma unroll
  for (int j = 0; j < 4; j++) { o[j] = (bf16_t)a[j]; o[4 + j] = (bf16_t)b[j]; }
  *(v8bf*)(d + i) = o;
}

__global__ __launch_bounds__(256) void convert_q_kernel(
    const float* __restrict__ q, bf16_t* __restrict__ qb)
{
  size_t i = ((size_t)blockIdx.x * 256 + threadIdx.x) * 8;
  v4f a = *(const v4f*)(q + i), b = *(const v4f*)(q + i + 4);
  v8bf o;
#pragma unroll
  for (int j = 0; j < 4; j++) { o[j] = (bf16_t)a[j]; o[4 + j] = (bf16_t)b[j]; }
  *(v8bf*)(qb + i) = o;
}

// rs[o] = -1e9 * sum_e W[o,e] + b[o]; rows 0..1023 = Wq/bq, 1024..2047 = Wk/bk (f32).
__global__ __launch_bounds__(256) void rowsum_kernel(
    const float* __restrict__ Wq, const float* __restrict__ bq,
    const float* __restrict__ Wk, const float* __restrict__ bk,
    float* __restrict__ rs)
{
  int w = threadIdx.x >> 6, l = threadIdx.x & 63;
  int row = blockIdx.x * 4 + w;
  int r = (row < 1024) ? row : row - 1024;
  const float* W = ((row < 1024) ? Wq : Wk) + (size_t)r * 1024 + l * 16;
  float s = 0.f;
#pragma unroll
  for (int i = 0; i < 4; i++) {
    v4f x = *(const v4f*)(W + i * 4);
    s += x[0] + x[1] + x[2] + x[3];
  }
#pragma unroll
  for (int sh = 1; sh < 64; sh <<= 1) s += __shfl_xor(s, sh, 64);
  if (l == 0) {
    float b = (row < 1024) ? bq[r] : bk[r];
    rs[row] = -1e9f * s + b;
  }
}

// C[m,n] = sum_k A[m,k]*W[n,k] + bias[n], A bf16 (M=16384, N=K=1024), 128x128
// tiles, double-buffered async staging. EPI 0: plain, masked row -> bias.
// EPI 1: per-head softmax, masked row -> softmax(rs). EPI 2: masked row -> 0, f32 out.
template <int EPI>
__global__ __launch_bounds__(256) void gemm_bt(
    const bf16_t* __restrict__ A, const bf16_t* __restrict__ Wb,
    const float* __restrict__ bias, const int* __restrict__ rowmask,
    const float* __restrict__ rs, void* __restrict__ Cout)
{
  constexpr int K = 1024, N = 1024;
  __shared__ __align__(16) bf16_t As[2][128 * 32];
  __shared__ __align__(16) bf16_t Bs[2][128 * 32];
  const int t = threadIdx.x;
  const int l = t & 63;
  const int w = t >> 6;
  const int wm = w >> 1, wn = w & 1;
  // XCD-aware remap: 8 col-tiles of one A row-panel -> same XCD, consecutive
  const int xcd = blockIdx.x & 7;
  const int seq = blockIdx.x >> 3;
  const int by = ((seq >> 3) << 3) + xcd;   // 0..127
  const int bx = seq & 7;                   // 0..7
  const int m0 = by << 7, n0 = bx << 7;

  const int c0 = t, c1 = t + 256;           // chunk -> row c>>2, k-off (c&3)*8
  const bf16_t* Ag0 = A + (size_t)(m0 + (c0 >> 2)) * K + (c0 & 3) * 8;
  const bf16_t* Ag1 = A + (size_t)(m0 + (c1 >> 2)) * K + (c1 & 3) * 8;
  const bf16_t* Bg0 = Wb + (size_t)(n0 + (c0 >> 2)) * K + (c0 & 3) * 8;
  const bf16_t* Bg1 = Wb + (size_t)(n0 + (c1 >> 2)) * K + (c1 & 3) * 8;

  const int lr = l & 15;
  const int kq = (l >> 4) * 8;
  const int aOff = (wm * 64 + lr) * 32 + kq;
  const int bOff = (wn * 64 + lr) * 32 + kq;

  v4f acc[4][4] = {};

  auto stage = [&](int kt, int b) {
    gl_lds16(Ag0 + kt, &As[b][c0 * 8]);
    gl_lds16(Ag1 + kt, &As[b][c1 * 8]);
    gl_lds16(Bg0 + kt, &Bs[b][c0 * 8]);
    gl_lds16(Bg1 + kt, &Bs[b][c1 * 8]);
  };
  auto compute = [&](const bf16_t* Asb, const bf16_t* Bsb) {
    v8bf af[4], bf4[4];
#pragma unroll
    for (int r = 0; r < 4; r++) af[r] = *(const v8bf*)(Asb + aOff + r * 512);
#pragma unroll
    for (int c = 0; c < 4; c++) bf4[c] = *(const v8bf*)(Bsb + bOff + c * 512);
#pragma unroll
    for (int r = 0; r < 4; r++)
#pragma unroll
      for (int c = 0; c < 4; c++)
        acc[r][c] = __builtin_amdgcn_mfma_f32_16x16x32_bf16(af[r], bf4[c], acc[r][c], 0, 0, 0);
  };

  stage(0, 0);
  for (int kt = 0; kt < K; kt += 64) {
    __syncthreads();                       // drains buf0 loads (in flight during prev compute)
    if (kt + 32 < K) stage(kt + 32, 1);    // prefetch -> buf1
    compute(As[0], Bs[0]);
    __syncthreads();                       // drains buf1 loads
    if (kt + 64 < K) stage(kt + 64, 0);    // prefetch -> buf0
    compute(As[1], Bs[1]);
  }

  // epilogue: C/D layout col = l&15, row = (l>>4)*4 + i
  const int rq = (l >> 4) * 4;
  float bcol[4], rscol[4]; int colg[4];
#pragma unroll
  for (int c = 0; c < 4; c++) {
    colg[c] = n0 + wn * 64 + c * 16 + lr;
    bcol[c] = bias[colg[c]];
    rscol[c] = (EPI == 1) ? rs[colg[c]] : 0.f;
  }
#pragma unroll
  for (int r = 0; r < 4; r++) {
    int rowBase = m0 + wm * 64 + r * 16 + rq;
#pragma unroll
    for (int i = 0; i < 4; i++) {
      int row = rowBase + i;
      int msk = rowmask[row];
      float vv[4];
#pragma unroll
      for (int c = 0; c < 4; c++) {
        float x = acc[r][c][i] + bcol[c];
        if (EPI == 0)      x = msk ? x : bcol[c];
        else if (EPI == 1) x = msk ? x : rscol[c];
        else               x = msk ? x : 0.f;
        vv[c] = x;
      }
      if (EPI == 1) {  // per-head softmax: 64 vals in this 16-lane group x 4 tiles
        float mx = fmaxf(fmaxf(vv[0], vv[1]), fmaxf(vv[2], vv[3]));
#pragma unroll
        for (int sh = 1; sh < 16; sh <<= 1) mx = fmaxf(mx, __shfl_xor(mx, sh, 64));
        float e0 = __expf(vv[0] - mx), e1 = __expf(vv[1] - mx);
        float e2 = __expf(vv[2] - mx), e3 = __expf(vv[3] - mx);
        float sum = e0 + e1 + e2 + e3;
#pragma unroll
        for (int sh = 1; sh < 16; sh <<= 1) sum += __shfl_xor(sum, sh, 64);
        float rinv = 1.0f / sum;
        vv[0] = e0 * rinv; vv[1] = e1 * rinv; vv[2] = e2 * rinv; vv[3] = e3 * rinv;
      }
#pragma unroll
      for (int c = 0; c < 4; c++) {
        size_t idx = (size_t)row * N + colg[c];
        if (EPI == 2) ((float*)Cout)[idx] = vv[c];
        else          ((bf16_t*)Cout)[idx] = (bf16_t)vv[c];
      }
    }
  }
}

// ctx[bh][d][e] += sum_{s chunk} kh[d]*vh[e];  kc[bh][d] += sum kh[d]  (f32 atomics)
__global__ __launch_bounds__(256) void ctx_partial(
    const bf16_t* __restrict__ kh, const bf16_t* __restrict__ vh,
    float* __restrict__ ctx, float* __restrict__ kc)
{
  __shared__ __align__(16) float khs[32][64];
  __shared__ __align__(16) float vhs[32][64];
  const int bh = blockIdx.x & 63;
  const int sp = blockIdx.x >> 6;
  const int b = bh >> 4, h = bh & 15;
  const int t = threadIdx.x;
  const int sl = t >> 3, d0 = (t & 7) * 8;
  const int dd = (t & 15) * 4, ee = (t >> 4) * 4;
  float acc[4][4] = {};
  float kcacc = 0.f;
  const size_t base = ((size_t)b * 4096) * 1024 + h * 64;
  const int sBeg = sp * (4096 / NSPLIT), sEnd = sBeg + 4096 / NSPLIT;
  for (int s0 = sBeg; s0 < sEnd; s0 += 32) {
    __syncthreads();
    v8bf kv = *(const v8bf*)(kh + base + (size_t)(s0 + sl) * 1024 + d0);
    v8bf vv = *(const v8bf*)(vh + base + (size_t)(s0 + sl) * 1024 + d0);
#pragma unroll
    for (int j = 0; j < 8; j++) { khs[sl][d0 + j] = (float)kv[j]; vhs[sl][d0 + j] = (float)vv[j]; }
    __syncthreads();
#pragma unroll 4
    for (int s = 0; s < 32; s++) {
      v4f kd = *(const v4f*)&khs[s][dd];
      v4f ve = *(const v4f*)&vhs[s][ee];
#pragma unroll
      for (int x = 0; x < 4; x++)
#pragma unroll
        for (int y = 0; y < 4; y++) acc[x][y] += kd[x] * ve[y];
    }
    if (t < 64) {
#pragma unroll 4
      for (int s = 0; s < 32; s++) kcacc += khs[s][t];
    }
  }
  float* cp = ctx + (size_t)bh * 4096;
#pragma unroll
  for (int x = 0; x < 4; x++)
#pragma unroll
    for (int y = 0; y < 4; y++) atomicAdd(&cp[(dd + x) * 64 + ee + y], acc[x][y]);
  if (t < 64) atomicAdd(&kc[bh * 64 + t], kcacc);
}

// outp = (qh @ ctx) / (qh . kc) + qh   per (b,h); safe to run IN-PLACE (outp==qh):
// each block fully reads its 256x64 chunk into LDS before any global write.
__global__ __launch_bounds__(256) void outpre_kernel(
    const bf16_t* __restrict__ qh, const float* __restrict__ ctx,
    const float* __restrict__ kc, bf16_t* __restrict__ outp)
{
  __shared__ __align__(16) bf16_t qt[64][256];
  __shared__ __align__(16) float ctxs[64][64];
  __shared__ float kcs[64];
  const int blk = blockIdx.x;
  const int st = blk & 15, h = (blk >> 4) & 15, b = blk >> 8;
  const int bh = b * 16 + h;
  const int t = threadIdx.x;
  const int s0 = st * 256;
  const size_t base = ((size_t)b * 4096 + s0) * 1024 + h * 64;
#pragma unroll
  for (int i = 0; i < 8; i++) {
    int cc = i * 256 + t;
    int row = cc >> 3, dd = (cc & 7) * 8;
    v8bf qv = *(const v8bf*)(qh + base + (size_t)row * 1024 + dd);
#pragma unroll
    for (int j = 0; j < 8; j++) qt[dd + j][row] = qv[j];
  }
  const float* cg = ctx + (size_t)bh * 4096;
#pragma unroll
  for (int i = 0; i < 4; i++) {
    int off = i * 1024 + t * 4;
    *(v4f*)((float*)ctxs + off) = *(const v4f*)(cg + off);
  }
  if (t < 64) kcs[t] = kc[bh * 64 + t];
  __syncthreads();

  const int e0 = (t & 3) * 16;
  const int rg = t >> 2;
  float at[4] = {};
  float acc[4][16] = {};
  for (int d = 0; d < 64; d++) {
    v4bf q4 = *(const v4bf*)&qt[d][rg * 4];
    float kcd = kcs[d];
    float qf[4];
#pragma unroll
    for (int j = 0; j < 4; j++) { qf[j] = (float)q4[j]; at[j] += qf[j] * kcd; }
    const float* cr = &ctxs[d][e0];
    v4f ca = *(const v4f*)cr, cb = *(const v4f*)(cr + 4);
    v4f cc3 = *(const v4f*)(cr + 8), cd = *(const v4f*)(cr + 12);
#pragma unroll
    for (int j = 0; j < 4; j++) {
#pragma unroll
      for (int i = 0; i < 4; i++) {
        acc[j][i]      += qf[j] * ca[i];
        acc[j][4 + i]  += qf[j] * cb[i];
        acc[j][8 + i]  += qf[j] * cc3[i];
        acc[j][12 + i] += qf[j] * cd[i];
      }
    }
  }
#pragma unroll
  for (int j = 0; j < 4; j++) {
    int row = rg * 4 + j;
    float rinv = 1.0f / at[j];
    bf16_t* op = outp + base + (size_t)row * 1024 + e0;
#pragma unroll
    for (int i = 0; i < 16; i++) op[i] = (bf16_t)(acc[j][i] * rinv + (float)qt[e0 + i][row]);
  }
}

extern "C" void kernel_launch(void* const* d_in, const int* in_sizes, int n_in,
                              void* d_out, int out_size, void* d_ws, size_t ws_size,
                              hipStream_t stream)
{
  const float* q  = (const float*)d_in[0];
  const float* k  = (const float*)d_in[1];
  const float* v  = (const float*)d_in[2];
  const int* qmask = (const int*)d_in[3];
  const int* kmask = (const int*)d_in[4];
  const float* Wq = (const float*)d_in[5];
  const float* bq = (const float*)d_in[6];
  const float* Wk = (const float*)d_in[7];
  const float* bk = (const float*)d_in[8];
  const float* Wv = (const float*)d_in[9];
  const float* bv = (const float*)d_in[10];
  const float* Wp = (const float*)d_in[11];
  const float* bp = (const float*)d_in[12];

  const int M = 16384;
  char* ws = (char*)d_ws;
  size_t off = 0;
  auto alloc = [&](size_t bytes) {
    void* p = ws + off; off += (bytes + 255) & ~(size_t)255; return p;
  };
  bf16_t* wb   = (bf16_t*)alloc(4 * 1048576 * 2);           // 8 MB: Wq,Wk,Wv,Wp bf16
  bf16_t* abuf = (bf16_t*)alloc((size_t)M * 1024 * 2);      // 33.5 MB: kh -> qh -> outp
  float* ctx   = (float*)alloc((64 * 4096 + 64 * 64) * 4);  // 1.06 MB: ctx + kc
  float* kc    = ctx + 64 * 4096;
  float* rs    = (float*)alloc(2048 * 4);
  // total ws ~= 43 MB (proven >= 49.3 usable in round 2)
  bf16_t* Wqb = wb, *Wkb = wb + 1048576, *Wvb = wb + 2097152, *Wpb = wb + 3145728;
  // d_out (67 MB f32) as scratch: lo = kb -> vh ; hi = vb -> qb ; final f32 C last
  bf16_t* lo = (bf16_t*)d_out;
  bf16_t* hi = (bf16_t*)((char*)d_out + 33554432);

  hipMemsetAsync(ctx, 0, (64 * 4096 + 64 * 64) * 4, stream);
  convert_w<<<2048, 256, 0, stream>>>(Wq, Wk, Wv, Wp, wb);
  rowsum_kernel<<<512, 256, 0, stream>>>(Wq, bq, Wk, bk, rs);
  convert_kv_kernel<<<16384, 256, 0, stream>>>(k, v, lo, hi);     // kb=lo, vb=hi

  const int gblocks = (M / 128) * (1024 / 128);  // 1024
  gemm_bt<1><<<gblocks, 256, 0, stream>>>(lo, Wkb, bk, kmask, rs + 1024, abuf); // kh
  gemm_bt<0><<<gblocks, 256, 0, stream>>>(hi, Wvb, bv, kmask, nullptr, lo);     // vh (kb dead)
  ctx_partial<<<64 * NSPLIT, 256, 0, stream>>>(abuf, lo, ctx, kc);
  convert_q_kernel<<<8192, 256, 0, stream>>>(q, hi);              // qb (vb dead)
  gemm_bt<1><<<gblocks, 256, 0, stream>>>(hi, Wqb, bq, qmask, rs, abuf);        // qh (kh dead)
  outpre_kernel<<<1024, 256, 0, stream>>>(abuf, ctx, kc, abuf);   // in-place -> outp
  gemm_bt<2><<<gblocks, 256, 0, stream>>>(abuf, Wpb, bp, qmask, nullptr, d_out);
}